// Round 4
// baseline (183.879 us; speedup 1.0000x reference)
//
#include <hip/hip_runtime.h>
#include <math.h>

#define XYD 16
#define ZD 16
#define SS 4096
#define VV 2048
#define BB 8
#define LL 32
#define WW 8
#define VC 32          // v-chunk for smoothing kernel
#define SM_STRIDE 257  // LDS tile stride (states dim +1 pad)

#define RINGD 4        // E-ring depth (slots)
#define ROWS 19        // 1 low guard + 16 planes + 2 high guard

#define LGKM0() asm volatile("s_waitcnt lgkmcnt(0)" ::: "memory")
#define SFENCE() __builtin_amdgcn_sched_barrier(0)

typedef unsigned short us8 __attribute__((ext_vector_type(8)));

__device__ __forceinline__ float b2f(unsigned short u) {
    union { unsigned int i; float f; } x; x.i = ((unsigned int)u) << 16; return x.f;
}
__device__ __forceinline__ unsigned short f2b(float f) {
    union { float f; unsigned int i; } x; x.f = f; return (unsigned short)(x.i >> 16);
}

// ---------------- Kernel 1: logZ[s] = logsumexp over V of emis_w[s,:] ----------------
__global__ void k_logZ(const float* __restrict__ emis_w, float* __restrict__ logZ) {
    int wave = threadIdx.x >> 6;
    int lane = threadIdx.x & 63;
    int row  = blockIdx.x * 4 + wave;
    const float* r = emis_w + (size_t)row * VV;
    float vals[32];
    float m = -INFINITY;
#pragma unroll
    for (int k = 0; k < 8; k++) {
        float4 f = ((const float4*)r)[k * 64 + lane];
        vals[k*4+0] = f.x; vals[k*4+1] = f.y; vals[k*4+2] = f.z; vals[k*4+3] = f.w;
    }
#pragma unroll
    for (int k = 0; k < 32; k++) m = fmaxf(m, vals[k]);
#pragma unroll
    for (int o = 32; o; o >>= 1) m = fmaxf(m, __shfl_xor(m, o));
    float sum = 0.f;
#pragma unroll
    for (int k = 0; k < 32; k++) sum += __expf(vals[k] - m);
#pragma unroll
    for (int o = 32; o; o >>= 1) sum += __shfl_xor(sum, o);
    if (lane == 0) logZ[row] = m + __logf(sum);
}

// ---------------- Kernel 2: smoothing + transpose, bf16 output -----------------------
__global__ void k_smooth(const float* __restrict__ emis_w, const float* __restrict__ logZ,
                         unsigned short* __restrict__ smTb) {
    __shared__ float tileT[VC * SM_STRIDE];  // [v][state]
    int z  = blockIdx.x;
    int v0 = blockIdx.y * VC;
    int tid = threadIdx.x;
    int rsub = tid >> 3;        // 0..31
    int c0   = (tid & 7) * 4;   // 0,4,..,28

#pragma unroll
    for (int it = 0; it < 8; it++) {
        int r  = it * 32 + rsub;         // plane state 0..255
        int sg = z * 256 + r;
        float lz = logZ[sg];
        float4 w = *(const float4*)(emis_w + (size_t)sg * VV + v0 + c0);
        tileT[(c0+0)*SM_STRIDE + r] = __expf(w.x - lz);
        tileT[(c0+1)*SM_STRIDE + r] = __expf(w.y - lz);
        tileT[(c0+2)*SM_STRIDE + r] = __expf(w.z - lz);
        tileT[(c0+3)*SM_STRIDE + r] = __expf(w.w - lz);
    }
    __syncthreads();

    int x = tid & 15, y = tid >> 4;
    int sxp = (x < 15) ? tid + 1  : tid;
    int sxm = (x > 0)  ? tid - 1  : tid;
    int syp = (y < 15) ? tid + 16 : tid;
    int sym = (y > 0)  ? tid - 16 : tid;
    unsigned short* o = smTb + (size_t)v0 * SS + z * 256 + tid;
#pragma unroll
    for (int i = 0; i < VC; i++) {
        const float* tb = tileT + i * SM_STRIDE;
        float s = tb[tid] + tb[sxp] + tb[sxm] + tb[syp] + tb[sym];
        o[(size_t)i * SS] = f2b(__logf(s * 0.2f));
    }
}

// ---------------- Kernel 3: all_emis[t,b,s] = sum_w smoothedT[tok][s] ----------------
__global__ void __launch_bounds__(512) k_emis(
    const int* __restrict__ stories, const unsigned short* __restrict__ smTb,
    float* __restrict__ all_emis) {
    int blk = blockIdx.x;
    int t = blk >> 3, b = blk & 7;
    int tid = threadIdx.x;
    int tok[WW];
#pragma unroll
    for (int w = 0; w < WW; w++) tok[w] = stories[(b * LL + t) * WW + w];
    int s0 = tid * 8;
    float acc[8] = {0.f,0.f,0.f,0.f,0.f,0.f,0.f,0.f};
#pragma unroll
    for (int w = 0; w < WW; w++) {
        if (tok[w] < VV) {  // wave-uniform
            us8 u = *(const us8*)(smTb + (size_t)tok[w] * SS + s0);
#pragma unroll
            for (int i = 0; i < 8; i++) acc[i] += b2f(u[i]);
        }
    }
    float* dst = all_emis + ((size_t)t * BB + b) * SS + s0;
    float4 lo = {acc[0], acc[1], acc[2], acc[3]};
    float4 hi = {acc[4], acc[5], acc[6], acc[7]};
    ((float4*)dst)[0] = lo;
    ((float4*)dst)[1] = hi;
}

// ---------------- Kernel 4: forward recurrence, barrier-free z-pipeline --------------
// One block per batch; 16 waves, wave z owns plane z (256 states, 4/thread).
// Gather form: new plane z needs old planes z, z+1, z+2 -> one-directional pipeline.
// Per-plane normalizer X_z (corner-state prediction); cross-plane reconciliation via
// fs1=exp(X_{z+1}-X_z), fs2=exp(X_{z+2}-X_z). Flag sync on a depth-4 LDS ring.
// This round: (a) merged 4-flag poll (parallel ds_reads, non-short-circuit OR, clamped
// edge indices + always-true thresholds); (b) early-read: at step tail, re-check next
// step's flags once; if ready (common), issue next step's neighbor reads immediately
// so their latency hides under the log/out tail; (c) s_sleep only on retry.
__global__ void __launch_bounds__(1024) k_forward(
    const float* __restrict__ trans_w, const float* __restrict__ prior_w,
    const float* __restrict__ all_emis, float* __restrict__ out) {
    __shared__ __align__(16) unsigned short Ering[RINGD][ROWS][256];  // ~38 KB
    __shared__ float Xring[RINGD][18];
    __shared__ int flags[16];
    __shared__ float pr[16];
    int b = blockIdx.x;
    int tid = threadIdx.x;
    int lane = tid & 63, z = tid >> 6;
    volatile int* vf = flags;

    // ---- zero-init rings (everything finite; guard rows stay 0 forever) ----
    {
        unsigned int* E4 = (unsigned int*)&Ering[0][0][0];
        const int n = RINGD * ROWS * 256 / 2;
        for (int i = tid; i < n; i += 1024) E4[i] = 0u;
        if (tid < RINGD * 18) (&Xring[0][0])[tid] = 0.f;
        if (tid < 16) flags[tid] = -1;
    }

    // clamped flag indices + threshold offsets (always-true for edge waves)
    const int iF1 = (z < 15) ? z + 1 : z;  const int cF1 = (z < 15) ? -1 : -1000000;
    const int iF2 = (z < 14) ? z + 2 : z;  const int cF2 = (z < 14) ? -1 : -1000000;
    const int iB1 = (z > 0)  ? z - 1 : z;  const int cB1 = (z > 0)  ? -3 : -1000000;
    const int iB2 = (z > 1)  ? z - 2 : z;  const int cB2 = (z > 1)  ? -3 : -1000000;

    // ---- transition prologue: pw (geometric order), am per state ----
    float pw[28], am[4];
    {
        float w7[28];
        const float4* t4 = (const float4*)(trans_w + (size_t)tid * 28);
#pragma unroll
        for (int k = 0; k < 7; k++) ((float4*)w7)[k] = t4[k];
#pragma unroll
        for (int i = 0; i < 4; i++) {
            int j = tid * 4 + i;
            int xx = j & 15, yy = (j >> 4) & 15, zz = j >> 8;
            bool val[7];
            val[0] = true;
            val[1] = (xx < 15); val[2] = (xx > 0);
            val[3] = (yy < 15); val[4] = (yy > 0);
            val[5] = (zz < 15); val[6] = (zz < 14);
            const float* rw = w7 + i * 7;
            float w[7]; int cnt = 0; float m = -INFINITY;
#pragma unroll
            for (int d = 0; d < 7; d++) { if (val[d]) { w[d] = rw[cnt++]; m = fmaxf(m, w[d]); } }
            float se = 0.f;
#pragma unroll
            for (int d = 0; d < 7; d++) if (val[d]) se += __expf(w[d] - m);
#pragma unroll
            for (int d = 0; d < 7; d++) pw[i*7+d] = val[d] ? __expf(w[d] - m) : 0.f;
            am[i] = -__logf(se);
        }
    }

    float4 pv = ((const float4*)prior_w)[tid];
    const float4* emp = (const float4*)(all_emis + (size_t)b * SS) + tid;
    float4 em = *emp;   // t=0

    // ---- priors log-softmax denominator (global; uses barriers, pre-pipeline) ----
    float lm = fmaxf(fmaxf(pv.x, pv.y), fmaxf(pv.z, pv.w));
#pragma unroll
    for (int o = 32; o; o >>= 1) lm = fmaxf(lm, __shfl_xor(lm, o));
    if (lane == 0) pr[z] = lm;
    __syncthreads();
    float gm = pr[0];
#pragma unroll
    for (int w = 1; w < 16; w++) gm = fmaxf(gm, pr[w]);
    __syncthreads();
    float ls = __expf(pv.x - gm) + __expf(pv.y - gm) + __expf(pv.z - gm) + __expf(pv.w - gm);
#pragma unroll
    for (int o = 32; o; o >>= 1) ls += __shfl_xor(ls, o);
    if (lane == 0) pr[z] = ls;
    __syncthreads();
    float gs = 0.f;
#pragma unroll
    for (int w = 0; w < 16; w++) gs += pr[w];
    float logZp = gm + __logf(gs);
    __syncthreads();   // ring zero-init + flag init globally visible

    // ---- step 0 ----
    float v0 = em.x + pv.x - logZp;
    float v1 = em.y + pv.y - logZp;
    float v2 = em.z + pv.z - logZp;
    float v3 = em.w + pv.w - logZp;
    float4* outp = (float4*)(out + (size_t)b * SS) + tid;
    *outp = make_float4(v0, v1, v2, v3);
    outp += (BB * SS) / 4;

    float g = __uint_as_float(__builtin_amdgcn_readfirstlane(__float_as_uint(v0)));
    float gp = g, gpp = g, Xcur = g;   // X_{z,0} = corner value
    float E0 = __expf(v0 - Xcur), E1 = __expf(v1 - Xcur);
    float E2 = __expf(v2 - Xcur), E3 = __expf(v3 - Xcur);
    {
        ushort4 E;
        E.x = f2b(E0); E.y = f2b(E1); E.z = f2b(E2); E.w = f2b(E3);
        *(ushort4*)(&Ering[0][z + 1][4 * lane]) = E;
        if (lane == 0) Xring[0][z] = Xcur;
    }
    LGKM0(); SFENCE();
    if (lane == 0) vf[z] = 0;

    emp += (BB * SS) / 4;
    float4 em_next = *emp;   // t=1

    // early-read state
    bool eok = false;
    ushort4 eYp = {0,0,0,0}, eYm = {0,0,0,0}, eZp = {0,0,0,0}, eZq = {0,0,0,0};
    float eX1 = 0.f, eX2 = 0.f;

    // ---- steps 1..L-1: flag-synced pipeline, no block barriers ----
#pragma unroll 4
    for (int t = 1; t < LL; t++) {
        int sR = (t - 1) & (RINGD - 1);
        int sW = t & (RINGD - 1);

        em = em_next;
        if (t < LL - 1) { emp += (BB * SS) / 4; em_next = *emp; }

        // pre-wait compute (no ring deps): prediction + K factors
        float Xnew = 2.f * gp - gpp;
        float dd = Xcur - Xnew;
        float s0 = em.x + am[0], s1 = em.y + am[1];
        float s2 = em.z + am[2], s3 = em.w + am[3];
        float K0 = __expf(s0 + dd), K1 = __expf(s1 + dd);
        float K2 = __expf(s2 + dd), K3 = __expf(s3 + dd);
        float cxw = __shfl_up(E3, 1);    // x-1 neighbor (pw==0 where invalid)
        float bx  = __shfl_down(E0, 1);  // x+1 neighbor

        ushort4 YpU, YmU, ZpU, ZqU; float XN1, XN2;
        if (eok) {
            YpU = eYp; YmU = eYm; ZpU = eZp; ZqU = eZq; XN1 = eX1; XN2 = eX2;
        } else {
            // merged poll: 4 parallel reads, one wait, non-short-circuit combine
            for (;;) {
                int fa = vf[iF1], fb = vf[iF2], fc = vf[iB1], fd = vf[iB2];
                int bad = (fa < t + cF1) | (fb < t + cF2) | (fc < t + cB1) | (fd < t + cB2);
                if (!bad) break;
                __builtin_amdgcn_s_sleep(1);
            }
            SFENCE();
            const unsigned short* pS = &Ering[sR][z + 1][4 * lane];
            YpU = *(const ushort4*)(pS + 16);
            YmU = *(const ushort4*)(pS - 16);
            ZpU = *(const ushort4*)(&Ering[sR][z + 2][4 * lane]);
            ZqU = *(const ushort4*)(&Ering[sR][z + 3][4 * lane]);
            XN1 = Xring[sR][z + 1];
            XN2 = Xring[sR][z + 2];
        }
        float fs1 = (z < 15) ? __expf(XN1 - Xcur) : 0.f;
        float fs2 = (z < 14) ? __expf(XN2 - Xcur) : 0.f;

        float a0 = E0*pw[0]  + E1*pw[1]  + cxw*pw[2] + b2f(YpU.x)*pw[3]  + b2f(YmU.x)*pw[4]
                 + fs1*(b2f(ZpU.x)*pw[5])  + fs2*(b2f(ZqU.x)*pw[6]);
        float a1 = E1*pw[7]  + E2*pw[8]  + E0*pw[9]  + b2f(YpU.y)*pw[10] + b2f(YmU.y)*pw[11]
                 + fs1*(b2f(ZpU.y)*pw[12]) + fs2*(b2f(ZqU.y)*pw[13]);
        float a2 = E2*pw[14] + E3*pw[15] + E1*pw[16] + b2f(YpU.z)*pw[17] + b2f(YmU.z)*pw[18]
                 + fs1*(b2f(ZpU.z)*pw[19]) + fs2*(b2f(ZqU.z)*pw[20]);
        float a3 = E3*pw[21] + bx*pw[22] + E2*pw[23] + b2f(YpU.w)*pw[24] + b2f(YmU.w)*pw[25]
                 + fs1*(b2f(ZpU.w)*pw[26]) + fs2*(b2f(ZqU.w)*pw[27]);

        // next-step E (log stays off this path): E = a * exp(em+am + Xcur - Xnew)
        E0 = a0 * K0; E1 = a1 * K1; E2 = a2 * K2; E3 = a3 * K3;
        {
            ushort4 E;
            E.x = f2b(E0); E.y = f2b(E1); E.z = f2b(E2); E.w = f2b(E3);
            *(ushort4*)(&Ering[sW][z + 1][4 * lane]) = E;
            if (lane == 0) Xring[sW][z] = Xnew;
        }
        LGKM0(); SFENCE();
        if (lane == 0) vf[z] = t;      // release: data committed before flag

        // tail (off the producer-consumer critical path)
        v0 = s0 + __logf(a0) + Xcur;
        v1 = s1 + __logf(a1) + Xcur;
        v2 = s2 + __logf(a2) + Xcur;
        v3 = s3 + __logf(a3) + Xcur;
        *outp = make_float4(v0, v1, v2, v3);
        outp += (BB * SS) / 4;

        g = __uint_as_float(__builtin_amdgcn_readfirstlane(__float_as_uint(v0)));
        gpp = gp; gp = g; Xcur = Xnew;

        // early attempt for step t+1 (single non-blocking check; flags are monotone)
        if (t < LL - 1) {
            int fa = vf[iF1], fb = vf[iF2], fc = vf[iB1], fd = vf[iB2];
            int bad = (fa < t + 1 + cF1) | (fb < t + 1 + cF2)
                    | (fc < t + 1 + cB1) | (fd < t + 1 + cB2);
            eok = !bad;
            if (eok) {
                SFENCE();
                const unsigned short* pS = &Ering[sW][z + 1][4 * lane];  // sW = next sR
                eYp = *(const ushort4*)(pS + 16);
                eYm = *(const ushort4*)(pS - 16);
                eZp = *(const ushort4*)(&Ering[sW][z + 2][4 * lane]);
                eZq = *(const ushort4*)(&Ering[sW][z + 3][4 * lane]);
                eX1 = Xring[sW][z + 1];
                eX2 = Xring[sW][z + 2];
            }
        }
    }
}

extern "C" void kernel_launch(void* const* d_in, const int* in_sizes, int n_in,
                              void* d_out, int out_size, void* d_ws, size_t ws_size,
                              hipStream_t stream) {
    const int*   stories = (const int*)d_in[0];
    const float* trans_w = (const float*)d_in[2];
    const float* emis_w  = (const float*)d_in[3];
    const float* prior_w = (const float*)d_in[4];
    float* out = (float*)d_out;

    char* ws = (char*)d_ws;
    unsigned short* smTb = (unsigned short*)(ws);                          // 16 MB bf16
    float* all_emis = (float*)(ws + (size_t)VV * SS * 2);                  // 4 MB
    float* logZ     = (float*)(ws + (size_t)VV * SS * 2 + (size_t)LL * BB * SS * 4);  // 16 KB

    k_logZ<<<SS / 4, 256, 0, stream>>>(emis_w, logZ);
    k_smooth<<<dim3(ZD, VV / VC), 256, 0, stream>>>(emis_w, logZ, smTb);
    k_emis<<<LL * BB, 512, 0, stream>>>(stories, smTb, all_emis);
    k_forward<<<BB, 1024, 0, stream>>>(trans_w, prior_w, all_emis, out);
}

// Round 5
// 179.599 us; speedup vs baseline: 1.0238x; 1.0238x over previous
//
#include <hip/hip_runtime.h>
#include <math.h>

#define XYD 16
#define ZD 16
#define SS 4096
#define VV 2048
#define BB 8
#define LL 32
#define WW 8
#define VC 32          // v-chunk for smoothing kernel
#define SM_STRIDE 257  // LDS tile stride (states dim +1 pad)

#define GUARD_L 16
#define GUARD_R 512
#define EBUF_N (GUARD_L + SS + GUARD_R)  // bf16 elems per buffer

// Raw workgroup barrier: LDS ordering only (no vmcnt drain of store acks/prefetches).
#define BAR() asm volatile("s_waitcnt lgkmcnt(0)\n\ts_barrier" ::: "memory")

typedef unsigned short us8 __attribute__((ext_vector_type(8)));

__device__ __forceinline__ float b2f(unsigned short u) {
    union { unsigned int i; float f; } x; x.i = ((unsigned int)u) << 16; return x.f;
}
__device__ __forceinline__ unsigned short f2b(float f) {
    union { float f; unsigned int i; } x; x.f = f; return (unsigned short)(x.i >> 16);
}

// ---------------- Kernel 1: logZ[s] = logsumexp over V of emis_w[s,:] ----------------
__global__ void k_logZ(const float* __restrict__ emis_w, float* __restrict__ logZ) {
    int wave = threadIdx.x >> 6;
    int lane = threadIdx.x & 63;
    int row  = blockIdx.x * 4 + wave;
    const float* r = emis_w + (size_t)row * VV;
    float vals[32];
    float m = -INFINITY;
#pragma unroll
    for (int k = 0; k < 8; k++) {
        float4 f = ((const float4*)r)[k * 64 + lane];
        vals[k*4+0] = f.x; vals[k*4+1] = f.y; vals[k*4+2] = f.z; vals[k*4+3] = f.w;
    }
#pragma unroll
    for (int k = 0; k < 32; k++) m = fmaxf(m, vals[k]);
#pragma unroll
    for (int o = 32; o; o >>= 1) m = fmaxf(m, __shfl_xor(m, o));
    float sum = 0.f;
#pragma unroll
    for (int k = 0; k < 32; k++) sum += __expf(vals[k] - m);
#pragma unroll
    for (int o = 32; o; o >>= 1) sum += __shfl_xor(sum, o);
    if (lane == 0) logZ[row] = m + __logf(sum);
}

// ---------------- Kernel 2: smoothing + transpose, bf16 output -----------------------
__global__ void k_smooth(const float* __restrict__ emis_w, const float* __restrict__ logZ,
                         unsigned short* __restrict__ smTb) {
    __shared__ float tileT[VC * SM_STRIDE];  // [v][state]
    int z  = blockIdx.x;
    int v0 = blockIdx.y * VC;
    int tid = threadIdx.x;
    int rsub = tid >> 3;        // 0..31
    int c0   = (tid & 7) * 4;   // 0,4,..,28

#pragma unroll
    for (int it = 0; it < 8; it++) {
        int r  = it * 32 + rsub;         // plane state 0..255
        int sg = z * 256 + r;
        float lz = logZ[sg];
        float4 w = *(const float4*)(emis_w + (size_t)sg * VV + v0 + c0);
        tileT[(c0+0)*SM_STRIDE + r] = __expf(w.x - lz);
        tileT[(c0+1)*SM_STRIDE + r] = __expf(w.y - lz);
        tileT[(c0+2)*SM_STRIDE + r] = __expf(w.z - lz);
        tileT[(c0+3)*SM_STRIDE + r] = __expf(w.w - lz);
    }
    __syncthreads();

    int x = tid & 15, y = tid >> 4;
    int sxp = (x < 15) ? tid + 1  : tid;
    int sxm = (x > 0)  ? tid - 1  : tid;
    int syp = (y < 15) ? tid + 16 : tid;
    int sym = (y > 0)  ? tid - 16 : tid;
    unsigned short* o = smTb + (size_t)v0 * SS + z * 256 + tid;
#pragma unroll
    for (int i = 0; i < VC; i++) {
        const float* tb = tileT + i * SM_STRIDE;
        float s = tb[tid] + tb[sxp] + tb[sxm] + tb[syp] + tb[sym];
        o[(size_t)i * SS] = f2b(__logf(s * 0.2f));
    }
}

// ---------------- Kernel 3: forward recurrence with fused emission gather ------------
// One block per batch; 1024 threads, 4 consecutive states/thread (16 waves).
// Round-2 barrier structure (proven fastest). The per-(t,b) emission sum over 8 tokens
// is fused here: 8 ushort4 gathers/thread, prefetched ONE STEP AHEAD into registers so
// HBM/L2 latency hides under the step; bf16 unpack-sum sits before the barrier, off
// the inter-wave critical path. k_emis and the 8 MB all_emis round-trip are gone.
__global__ void __launch_bounds__(1024) k_forward(
    const int* __restrict__ stories, const float* __restrict__ trans_w,
    const float* __restrict__ prior_w, const unsigned short* __restrict__ smTb,
    float* __restrict__ out) {
    __shared__ __align__(16) unsigned short Ebuf[2][EBUF_N];
    __shared__ float red2[2];
    __shared__ float pr[16];
    __shared__ int stl[LL * WW];
    int b = blockIdx.x;
    int tid = threadIdx.x;
    int lane = tid & 63, wid = tid >> 6;

    if (tid < GUARD_L) { Ebuf[0][tid] = 0; Ebuf[1][tid] = 0; }
    if (tid < GUARD_R) {
        Ebuf[0][GUARD_L + SS + tid] = 0;
        Ebuf[1][GUARD_L + SS + tid] = 0;
    }
    if (tid < LL * WW) stl[tid] = stories[b * (LL * WW) + tid];

    // ---- transition prologue: pw (geometric order), am per state ----
    float pw[28], am[4];
    {
        float w7[28];
        const float4* t4 = (const float4*)(trans_w + (size_t)tid * 28);
#pragma unroll
        for (int k = 0; k < 7; k++) ((float4*)w7)[k] = t4[k];
#pragma unroll
        for (int i = 0; i < 4; i++) {
            int j = tid * 4 + i;
            int xx = j & 15, yy = (j >> 4) & 15, zz = j >> 8;
            bool val[7];
            val[0] = true;
            val[1] = (xx < 15); val[2] = (xx > 0);
            val[3] = (yy < 15); val[4] = (yy > 0);
            val[5] = (zz < 15); val[6] = (zz < 14);
            const float* rw = w7 + i * 7;
            float w[7]; int cnt = 0; float m = -INFINITY;
#pragma unroll
            for (int d = 0; d < 7; d++) { if (val[d]) { w[d] = rw[cnt++]; m = fmaxf(m, w[d]); } }
            float se = 0.f;
#pragma unroll
            for (int d = 0; d < 7; d++) if (val[d]) se += __expf(w[d] - m);
#pragma unroll
            for (int d = 0; d < 7; d++) pw[i*7+d] = val[d] ? __expf(w[d] - m) : 0.f;
            am[i] = -__logf(se);
        }
    }

    float4 pv = ((const float4*)prior_w)[tid];

    // ---- priors log-softmax denominator (also makes stl visible) ----
    float lm = fmaxf(fmaxf(pv.x, pv.y), fmaxf(pv.z, pv.w));
#pragma unroll
    for (int o = 32; o; o >>= 1) lm = fmaxf(lm, __shfl_xor(lm, o));
    if (lane == 0) pr[wid] = lm;
    __syncthreads();
    float gm = pr[0];
#pragma unroll
    for (int w = 1; w < 16; w++) gm = fmaxf(gm, pr[w]);
    __syncthreads();
    float ls = __expf(pv.x - gm) + __expf(pv.y - gm) + __expf(pv.z - gm) + __expf(pv.w - gm);
#pragma unroll
    for (int o = 32; o; o >>= 1) ls += __shfl_xor(ls, o);
    if (lane == 0) pr[wid] = ls;
    __syncthreads();
    float gs = 0.f;
#pragma unroll
    for (int w = 0; w < 16; w++) gs += pr[w];
    float logZp = gm + __logf(gs);

    // ---- emission gather for t=0 (synchronous) ----
    const size_t gidx = 4 * (size_t)tid;   // elem offset of this thread's 4 states
    ushort4 gb[WW];
#pragma unroll
    for (int w = 0; w < WW; w++) {
        int tk = stl[w];
        if (tk < VV) gb[w] = *(const ushort4*)(smTb + (size_t)tk * SS + gidx);
        else         gb[w] = make_ushort4(0, 0, 0, 0);
    }
    float emx = 0.f, emy = 0.f, emz = 0.f, emw = 0.f;
#pragma unroll
    for (int w = 0; w < WW; w++) {
        emx += b2f(gb[w].x); emy += b2f(gb[w].y);
        emz += b2f(gb[w].z); emw += b2f(gb[w].w);
    }

    // ---- step 0 (store deferred into loop) ----
    float v0 = emx + pv.x - logZp;
    float v1 = emy + pv.y - logZp;
    float v2 = emz + pv.z - logZp;
    float v3 = emw + pv.w - logZp;
    float4 ov_prev = {v0, v1, v2, v3};
    float4* outp = (float4*)(out + (size_t)b * SS) + tid;  // slot for t=0

    if (tid == 0) red2[0] = v0;   // g_0
    __syncthreads();
    float g1 = red2[0];
    float XpPrev = g1;
    float E0 = __expf(v0 - XpPrev), E1 = __expf(v1 - XpPrev);
    float E2 = __expf(v2 - XpPrev), E3 = __expf(v3 - XpPrev);
    {
        ushort4 E;
        E.x = f2b(E0); E.y = f2b(E1); E.z = f2b(E2); E.w = f2b(E3);
        *(ushort4*)(&Ebuf[0][GUARD_L + 4 * tid]) = E;
    }

    // prefetch gather for t=1
#pragma unroll
    for (int w = 0; w < WW; w++) {
        int tk = stl[WW + w];
        if (tk < VV) gb[w] = *(const ushort4*)(smTb + (size_t)tk * SS + gidx);
        else         gb[w] = make_ushort4(0, 0, 0, 0);
    }

    // ---- steps 1..L-1: one raw barrier per step; out-store one step behind ----
    int cur = 0;
#pragma unroll 2
    for (int t = 1; t < LL; t++) {
        // pre-barrier: finalize em_t from prefetched gb, then issue t+1's gathers.
        // (register/global only — off the Ebuf critical path)
        emx = 0.f; emy = 0.f; emz = 0.f; emw = 0.f;
#pragma unroll
        for (int w = 0; w < WW; w++) {
            emx += b2f(gb[w].x); emy += b2f(gb[w].y);
            emz += b2f(gb[w].z); emw += b2f(gb[w].w);
        }
        if (t < LL - 1) {
#pragma unroll
            for (int w = 0; w < WW; w++) {
                int tk = stl[(t + 1) * WW + w];
                if (tk < VV) gb[w] = *(const ushort4*)(smTb + (size_t)tk * SS + gidx);
                else         gb[w] = make_ushort4(0, 0, 0, 0);
            }
        }

        // x-neighbor exchange in registers (DPP wave shift; invalid lanes have pw==0)
        float cxw = __shfl_up(E3, 1);    // state 4*tid-1
        float bx  = __shfl_down(E0, 1);  // state 4*tid+4

        BAR();
        *outp = ov_prev;                    // store v_{t-1}; ack never drained in-loop
        outp += (BB * SS) / 4;

        float g0 = red2[cur];
        float Xp = 2.f * g0 - g1;
        float dd = XpPrev - Xp;

        // early exp factors: depend only on em (prefetched) and broadcast g0
        float s0 = emx + am[0], s1 = emy + am[1];
        float s2 = emz + am[2], s3 = emw + am[3];
        float K0 = __expf(s0 + dd), K1 = __expf(s1 + dd);
        float K2 = __expf(s2 + dd), K3 = __expf(s3 + dd);

        const unsigned short* Eb = Ebuf[cur] + GUARD_L + 4 * tid;
        ushort4 YpU = *(const ushort4*)(Eb + 16);
        ushort4 YmU = *(const ushort4*)(Eb - 16);
        ushort4 ZpU = *(const ushort4*)(Eb + 256);
        ushort4 ZqU = *(const ushort4*)(Eb + 512);

        float a0 = E0*pw[0]  + E1*pw[1]  + cxw*pw[2] + b2f(YpU.x)*pw[3]  + b2f(YmU.x)*pw[4]  + b2f(ZpU.x)*pw[5]  + b2f(ZqU.x)*pw[6];
        float a1 = E1*pw[7]  + E2*pw[8]  + E0*pw[9]  + b2f(YpU.y)*pw[10] + b2f(YmU.y)*pw[11] + b2f(ZpU.y)*pw[12] + b2f(ZqU.y)*pw[13];
        float a2 = E2*pw[14] + E3*pw[15] + E1*pw[16] + b2f(YpU.z)*pw[17] + b2f(YmU.z)*pw[18] + b2f(ZpU.z)*pw[19] + b2f(ZqU.z)*pw[20];
        float a3 = E3*pw[21] + bx*pw[22] + E2*pw[23] + b2f(YpU.w)*pw[24] + b2f(YmU.w)*pw[25] + b2f(ZpU.w)*pw[26] + b2f(ZqU.w)*pw[27];

        // next-step E written immediately (log path is off the critical chain):
        // exp(v - Xp) = a * exp(em + am + XpPrev - Xp)
        E0 = a0 * K0; E1 = a1 * K1; E2 = a2 * K2; E3 = a3 * K3;
        {
            ushort4 E;
            E.x = f2b(E0); E.y = f2b(E1); E.z = f2b(E2); E.w = f2b(E3);
            *(ushort4*)(&Ebuf[cur ^ 1][GUARD_L + 4 * tid]) = E;
        }

        v0 = s0 + __logf(a0) + XpPrev;
        v1 = s1 + __logf(a1) + XpPrev;
        v2 = s2 + __logf(a2) + XpPrev;
        v3 = s3 + __logf(a3) + XpPrev;
        ov_prev.x = v0; ov_prev.y = v1; ov_prev.z = v2; ov_prev.w = v3;

        if (tid == 0) red2[cur ^ 1] = v0;  // g_t

        g1 = g0; XpPrev = Xp; cur ^= 1;
    }
    *outp = ov_prev;   // t = LL-1
}

extern "C" void kernel_launch(void* const* d_in, const int* in_sizes, int n_in,
                              void* d_out, int out_size, void* d_ws, size_t ws_size,
                              hipStream_t stream) {
    const int*   stories = (const int*)d_in[0];
    const float* trans_w = (const float*)d_in[2];
    const float* emis_w  = (const float*)d_in[3];
    const float* prior_w = (const float*)d_in[4];
    float* out = (float*)d_out;

    char* ws = (char*)d_ws;
    unsigned short* smTb = (unsigned short*)(ws);                 // 16 MB bf16
    float* logZ = (float*)(ws + (size_t)VV * SS * 2);             // 16 KB

    k_logZ<<<SS / 4, 256, 0, stream>>>(emis_w, logZ);
    k_smooth<<<dim3(ZD, VV / VC), 256, 0, stream>>>(emis_w, logZ, smTb);
    k_forward<<<BB, 1024, 0, stream>>>(stories, trans_w, prior_w, smTb, out);
}

// Round 6
// 148.093 us; speedup vs baseline: 1.2416x; 1.2127x over previous
//
#include <hip/hip_runtime.h>
#include <math.h>

#define XYD 16
#define ZD 16
#define SS 4096
#define VV 2048
#define BB 8
#define LL 32
#define WW 8
#define VC 32          // v-chunk for smoothing kernel
#define SM_STRIDE 258  // LDS tile stride (even -> aligned b64 reads; 258%32=2 -> <=2-way)

#define GUARD_L 16
#define GUARD_R 512
#define EBUF_N (GUARD_L + SS + GUARD_R)  // bf16 elems per buffer

// Raw workgroup barrier: LDS ordering only (no vmcnt drain of store acks/prefetches).
#define BAR() asm volatile("s_waitcnt lgkmcnt(0)\n\ts_barrier" ::: "memory")

typedef unsigned short us8 __attribute__((ext_vector_type(8)));

__device__ __forceinline__ float b2f(unsigned short u) {
    union { unsigned int i; float f; } x; x.i = ((unsigned int)u) << 16; return x.f;
}
__device__ __forceinline__ unsigned short f2b(float f) {
    union { float f; unsigned int i; } x; x.f = f; return (unsigned short)(x.i >> 16);
}

// ---------------- Kernel 1a (q-path): q[s][v] = exp(w - logsumexp) in bf16 -----------
__global__ void k_prob(const float* __restrict__ emis_w, unsigned short* __restrict__ qb) {
    int wave = threadIdx.x >> 6;
    int lane = threadIdx.x & 63;
    int row  = blockIdx.x * 4 + wave;
    const float* r = emis_w + (size_t)row * VV;
    float vals[32];
    float m = -INFINITY;
#pragma unroll
    for (int k = 0; k < 8; k++) {
        float4 f = ((const float4*)r)[k * 64 + lane];
        vals[k*4+0] = f.x; vals[k*4+1] = f.y; vals[k*4+2] = f.z; vals[k*4+3] = f.w;
    }
#pragma unroll
    for (int k = 0; k < 32; k++) m = fmaxf(m, vals[k]);
#pragma unroll
    for (int o = 32; o; o >>= 1) m = fmaxf(m, __shfl_xor(m, o));
    float sum = 0.f;
#pragma unroll
    for (int k = 0; k < 32; k++) sum += __expf(vals[k] - m);
#pragma unroll
    for (int o = 32; o; o >>= 1) sum += __shfl_xor(sum, o);
    float lz = m + __logf(sum);          // all lanes hold it (xor-reduce)
    unsigned short* qr = qb + (size_t)row * VV;
#pragma unroll
    for (int k = 0; k < 8; k++) {
        ushort4 q;
        q.x = f2b(__expf(vals[k*4+0] - lz));
        q.y = f2b(__expf(vals[k*4+1] - lz));
        q.z = f2b(__expf(vals[k*4+2] - lz));
        q.w = f2b(__expf(vals[k*4+3] - lz));
        ((ushort4*)qr)[k * 64 + lane] = q;
    }
}

// ---------------- Kernel 1b (fallback): logZ only ------------------------------------
__global__ void k_logZ(const float* __restrict__ emis_w, float* __restrict__ logZ) {
    int wave = threadIdx.x >> 6;
    int lane = threadIdx.x & 63;
    int row  = blockIdx.x * 4 + wave;
    const float* r = emis_w + (size_t)row * VV;
    float vals[32];
    float m = -INFINITY;
#pragma unroll
    for (int k = 0; k < 8; k++) {
        float4 f = ((const float4*)r)[k * 64 + lane];
        vals[k*4+0] = f.x; vals[k*4+1] = f.y; vals[k*4+2] = f.z; vals[k*4+3] = f.w;
    }
#pragma unroll
    for (int k = 0; k < 32; k++) m = fmaxf(m, vals[k]);
#pragma unroll
    for (int o = 32; o; o >>= 1) m = fmaxf(m, __shfl_xor(m, o));
    float sum = 0.f;
#pragma unroll
    for (int k = 0; k < 32; k++) sum += __expf(vals[k] - m);
#pragma unroll
    for (int o = 32; o; o >>= 1) sum += __shfl_xor(sum, o);
    if (lane == 0) logZ[row] = m + __logf(sum);
}

// ---------------- shared phase 2: 5-point stencil + log, 2 states/thread -------------
// Thread u=tid&127 owns states {2u,2u+1} of the plane; vh=tid>>7 selects 16 v's.
// Clamped-index LDS reads reproduce the verified clamp-to-self edge semantics;
// b64 center/y reads, packed ushort2 stores. 5 LDS instrs per 2 outputs (was 10).
__device__ __forceinline__ void smooth_phase2(const float* __restrict__ tileT,
                                              unsigned short* __restrict__ smTb,
                                              int z, int v0, int tid) {
    int u = tid & 127, vh = tid >> 7;
    int s0 = 2 * u;
    int e = s0 & 15, y0 = s0 >> 4;
    int ixm = (e > 0)   ? s0 - 1  : s0;       // x-1 of state A (clamp -> A)
    int ixp = (e < 14)  ? s0 + 2  : s0 + 1;   // x+1 of state B (clamp -> B)
    int iym = (y0 > 0)  ? s0 - 16 : s0;       // y-1 pair (clamp -> A,B)
    int iyp = (y0 < 15) ? s0 + 16 : s0;       // y+1 pair
    unsigned int* o = (unsigned int*)(smTb + (size_t)(v0 + vh * 16) * SS + z * 256 + s0);
#pragma unroll
    for (int i = 0; i < 16; i++) {
        const float* tb = tileT + (vh * 16 + i) * SM_STRIDE;
        float2 c01 = *(const float2*)(tb + s0);
        float xmv = tb[ixm];
        float xpv = tb[ixp];
        float2 ymv = *(const float2*)(tb + iym);
        float2 ypv = *(const float2*)(tb + iyp);
        float sA = c01.x + c01.y + xmv + ymv.x + ypv.x;
        float sB = c01.x + c01.y + xpv + ymv.y + ypv.y;
        unsigned int qa = (unsigned int)f2b(__logf(sA * 0.2f));
        unsigned int qc = (unsigned int)f2b(__logf(sB * 0.2f));
        o[(size_t)i * (SS / 2)] = qa | (qc << 16);
    }
}

// ---------------- Kernel 2a (q-path): bf16 q in, no exp, no logZ ---------------------
__global__ void k_smooth_q(const unsigned short* __restrict__ qb,
                           unsigned short* __restrict__ smTb) {
    __shared__ float tileT[VC * SM_STRIDE];  // [v][state]
    int z  = blockIdx.x;
    int v0 = blockIdx.y * VC;
    int tid = threadIdx.x;
    int rsub = tid >> 3;        // 0..31
    int c0   = (tid & 7) * 4;   // 0,4,..,28
#pragma unroll
    for (int it = 0; it < 8; it++) {
        int r  = it * 32 + rsub;
        int sg = z * 256 + r;
        ushort4 u4 = *(const ushort4*)(qb + (size_t)sg * VV + v0 + c0);
        tileT[(c0+0)*SM_STRIDE + r] = b2f(u4.x);
        tileT[(c0+1)*SM_STRIDE + r] = b2f(u4.y);
        tileT[(c0+2)*SM_STRIDE + r] = b2f(u4.z);
        tileT[(c0+3)*SM_STRIDE + r] = b2f(u4.w);
    }
    __syncthreads();
    smooth_phase2(tileT, smTb, z, v0, tid);
}

// ---------------- Kernel 2b (fallback): fp32 emis + logZ in --------------------------
__global__ void k_smooth_f(const float* __restrict__ emis_w, const float* __restrict__ logZ,
                           unsigned short* __restrict__ smTb) {
    __shared__ float tileT[VC * SM_STRIDE];
    int z  = blockIdx.x;
    int v0 = blockIdx.y * VC;
    int tid = threadIdx.x;
    int rsub = tid >> 3;
    int c0   = (tid & 7) * 4;
#pragma unroll
    for (int it = 0; it < 8; it++) {
        int r  = it * 32 + rsub;
        int sg = z * 256 + r;
        float lzv = logZ[sg];
        float4 w = *(const float4*)(emis_w + (size_t)sg * VV + v0 + c0);
        tileT[(c0+0)*SM_STRIDE + r] = __expf(w.x - lzv);
        tileT[(c0+1)*SM_STRIDE + r] = __expf(w.y - lzv);
        tileT[(c0+2)*SM_STRIDE + r] = __expf(w.z - lzv);
        tileT[(c0+3)*SM_STRIDE + r] = __expf(w.w - lzv);
    }
    __syncthreads();
    smooth_phase2(tileT, smTb, z, v0, tid);
}

// ---------------- Kernel 3: all_emis[t,b,s] = sum_w smoothedT[tok][s] ----------------
__global__ void __launch_bounds__(512) k_emis(
    const int* __restrict__ stories, const unsigned short* __restrict__ smTb,
    float* __restrict__ all_emis) {
    int blk = blockIdx.x;
    int t = blk >> 3, b = blk & 7;
    int tid = threadIdx.x;
    int tok[WW];
#pragma unroll
    for (int w = 0; w < WW; w++) tok[w] = stories[(b * LL + t) * WW + w];
    int s0 = tid * 8;
    float acc[8] = {0.f,0.f,0.f,0.f,0.f,0.f,0.f,0.f};
#pragma unroll
    for (int w = 0; w < WW; w++) {
        if (tok[w] < VV) {  // wave-uniform
            us8 u = *(const us8*)(smTb + (size_t)tok[w] * SS + s0);
#pragma unroll
            for (int i = 0; i < 8; i++) acc[i] += b2f(u[i]);
        }
    }
    float* dst = all_emis + ((size_t)t * BB + b) * SS + s0;
    float4 lo = {acc[0], acc[1], acc[2], acc[3]};
    float4 hi = {acc[4], acc[5], acc[6], acc[7]};
    ((float4*)dst)[0] = lo;
    ((float4*)dst)[1] = hi;
}

// ---------------- Kernel 4: forward recurrence (exact round-2 structure) -------------
__global__ void __launch_bounds__(1024) k_forward(
    const float* __restrict__ trans_w, const float* __restrict__ prior_w,
    const float* __restrict__ all_emis, float* __restrict__ out) {
    __shared__ __align__(16) unsigned short Ebuf[2][EBUF_N];
    __shared__ float red2[2];
    __shared__ float pr[16];
    int b = blockIdx.x;
    int tid = threadIdx.x;
    int lane = tid & 63, wid = tid >> 6;

    if (tid < GUARD_L) { Ebuf[0][tid] = 0; Ebuf[1][tid] = 0; }
    if (tid < GUARD_R) {
        Ebuf[0][GUARD_L + SS + tid] = 0;
        Ebuf[1][GUARD_L + SS + tid] = 0;
    }

    float pw[28], am[4];
    {
        float w7[28];
        const float4* t4 = (const float4*)(trans_w + (size_t)tid * 28);
#pragma unroll
        for (int k = 0; k < 7; k++) ((float4*)w7)[k] = t4[k];
#pragma unroll
        for (int i = 0; i < 4; i++) {
            int j = tid * 4 + i;
            int xx = j & 15, yy = (j >> 4) & 15, zz = j >> 8;
            bool val[7];
            val[0] = true;
            val[1] = (xx < 15); val[2] = (xx > 0);
            val[3] = (yy < 15); val[4] = (yy > 0);
            val[5] = (zz < 15); val[6] = (zz < 14);
            const float* rw = w7 + i * 7;
            float w[7]; int cnt = 0; float m = -INFINITY;
#pragma unroll
            for (int d = 0; d < 7; d++) { if (val[d]) { w[d] = rw[cnt++]; m = fmaxf(m, w[d]); } }
            float se = 0.f;
#pragma unroll
            for (int d = 0; d < 7; d++) if (val[d]) se += __expf(w[d] - m);
#pragma unroll
            for (int d = 0; d < 7; d++) pw[i*7+d] = val[d] ? __expf(w[d] - m) : 0.f;
            am[i] = -__logf(se);
        }
    }

    float4 pv = ((const float4*)prior_w)[tid];
    const float4* emp = (const float4*)(all_emis + (size_t)b * SS) + tid;
    float4 em = *emp;   // t=0

    float lm = fmaxf(fmaxf(pv.x, pv.y), fmaxf(pv.z, pv.w));
#pragma unroll
    for (int o = 32; o; o >>= 1) lm = fmaxf(lm, __shfl_xor(lm, o));
    if (lane == 0) pr[wid] = lm;
    __syncthreads();
    float gm = pr[0];
#pragma unroll
    for (int w = 1; w < 16; w++) gm = fmaxf(gm, pr[w]);
    __syncthreads();
    float ls = __expf(pv.x - gm) + __expf(pv.y - gm) + __expf(pv.z - gm) + __expf(pv.w - gm);
#pragma unroll
    for (int o = 32; o; o >>= 1) ls += __shfl_xor(ls, o);
    if (lane == 0) pr[wid] = ls;
    __syncthreads();
    float gs = 0.f;
#pragma unroll
    for (int w = 0; w < 16; w++) gs += pr[w];
    float logZp = gm + __logf(gs);

    float v0 = em.x + pv.x - logZp;
    float v1 = em.y + pv.y - logZp;
    float v2 = em.z + pv.z - logZp;
    float v3 = em.w + pv.w - logZp;
    float4 ov_prev = {v0, v1, v2, v3};
    float4* outp = (float4*)(out + (size_t)b * SS) + tid;

    if (tid == 0) red2[0] = v0;
    __syncthreads();
    float g1 = red2[0];
    float XpPrev = g1;
    float E0 = __expf(v0 - XpPrev), E1 = __expf(v1 - XpPrev);
    float E2 = __expf(v2 - XpPrev), E3 = __expf(v3 - XpPrev);
    {
        ushort4 E;
        E.x = f2b(E0); E.y = f2b(E1); E.z = f2b(E2); E.w = f2b(E3);
        *(ushort4*)(&Ebuf[0][GUARD_L + 4 * tid]) = E;
    }

    emp += (BB * SS) / 4;
    float4 em_next = *emp;   // t=1

    int cur = 0;
#pragma unroll 2
    for (int t = 1; t < LL; t++) {
        BAR();
        *outp = ov_prev;
        outp += (BB * SS) / 4;

        em = em_next;
        if (t < LL - 1) { emp += (BB * SS) / 4; em_next = *emp; }

        float cxw = __shfl_up(E3, 1);
        float bx  = __shfl_down(E0, 1);

        float g0 = red2[cur];
        float Xp = 2.f * g0 - g1;
        float dd = XpPrev - Xp;

        float s0 = em.x + am[0], s1 = em.y + am[1];
        float s2 = em.z + am[2], s3 = em.w + am[3];
        float K0 = __expf(s0 + dd), K1 = __expf(s1 + dd);
        float K2 = __expf(s2 + dd), K3 = __expf(s3 + dd);

        const unsigned short* Eb = Ebuf[cur] + GUARD_L + 4 * tid;
        ushort4 YpU = *(const ushort4*)(Eb + 16);
        ushort4 YmU = *(const ushort4*)(Eb - 16);
        ushort4 ZpU = *(const ushort4*)(Eb + 256);
        ushort4 ZqU = *(const ushort4*)(Eb + 512);

        float a0 = E0*pw[0]  + E1*pw[1]  + cxw*pw[2] + b2f(YpU.x)*pw[3]  + b2f(YmU.x)*pw[4]  + b2f(ZpU.x)*pw[5]  + b2f(ZqU.x)*pw[6];
        float a1 = E1*pw[7]  + E2*pw[8]  + E0*pw[9]  + b2f(YpU.y)*pw[10] + b2f(YmU.y)*pw[11] + b2f(ZpU.y)*pw[12] + b2f(ZqU.y)*pw[13];
        float a2 = E2*pw[14] + E3*pw[15] + E1*pw[16] + b2f(YpU.z)*pw[17] + b2f(YmU.z)*pw[18] + b2f(ZpU.z)*pw[19] + b2f(ZqU.z)*pw[20];
        float a3 = E3*pw[21] + bx*pw[22] + E2*pw[23] + b2f(YpU.w)*pw[24] + b2f(YmU.w)*pw[25] + b2f(ZpU.w)*pw[26] + b2f(ZqU.w)*pw[27];

        E0 = a0 * K0; E1 = a1 * K1; E2 = a2 * K2; E3 = a3 * K3;
        {
            ushort4 E;
            E.x = f2b(E0); E.y = f2b(E1); E.z = f2b(E2); E.w = f2b(E3);
            *(ushort4*)(&Ebuf[cur ^ 1][GUARD_L + 4 * tid]) = E;
        }

        v0 = s0 + __logf(a0) + XpPrev;
        v1 = s1 + __logf(a1) + XpPrev;
        v2 = s2 + __logf(a2) + XpPrev;
        v3 = s3 + __logf(a3) + XpPrev;
        ov_prev.x = v0; ov_prev.y = v1; ov_prev.z = v2; ov_prev.w = v3;

        if (tid == 0) red2[cur ^ 1] = v0;

        g1 = g0; XpPrev = Xp; cur ^= 1;
    }
    *outp = ov_prev;
}

extern "C" void kernel_launch(void* const* d_in, const int* in_sizes, int n_in,
                              void* d_out, int out_size, void* d_ws, size_t ws_size,
                              hipStream_t stream) {
    const int*   stories = (const int*)d_in[0];
    const float* trans_w = (const float*)d_in[2];
    const float* emis_w  = (const float*)d_in[3];
    const float* prior_w = (const float*)d_in[4];
    float* out = (float*)d_out;

    char* ws = (char*)d_ws;
    unsigned short* smTb = (unsigned short*)(ws);                              // 16 MB
    float* all_emis = (float*)(ws + (size_t)VV * SS * 2);                      // 4 MB

    if (ws_size >= (size_t)36 * 1024 * 1024) {
        unsigned short* qb = (unsigned short*)(ws + (size_t)20 * 1024 * 1024); // 16 MB
        k_prob<<<SS / 4, 256, 0, stream>>>(emis_w, qb);
        k_smooth_q<<<dim3(ZD, VV / VC), 256, 0, stream>>>(qb, smTb);
    } else {
        float* logZ = (float*)(ws + (size_t)VV * SS * 2 + (size_t)LL * BB * SS * 4);
        k_logZ<<<SS / 4, 256, 0, stream>>>(emis_w, logZ);
        k_smooth_f<<<dim3(ZD, VV / VC), 256, 0, stream>>>(emis_w, logZ, smTb);
    }
    k_emis<<<LL * BB, 512, 0, stream>>>(stories, smTb, all_emis);
    k_forward<<<BB, 1024, 0, stream>>>(trans_w, prior_w, all_emis, out);
}